// Round 10
// baseline (921.527 us; speedup 1.0000x reference)
//
#include <hip/hip_runtime.h>
#include <math.h>

#define D_DIM 1024
#define CL 512   // scan chunk length

typedef __attribute__((ext_vector_type(8))) short short8;
typedef __attribute__((ext_vector_type(4))) float f32x4;
typedef unsigned short u16;

__device__ __forceinline__ u16 f2bf(float f) {
    unsigned int u = __float_as_uint(f);
    u += 0x7fff + ((u >> 16) & 1);          // round-to-nearest-even
    return (u16)(u >> 16);
}
__device__ __forceinline__ float bf2f(u16 h) {
    return __uint_as_float((unsigned int)h << 16);
}

#define GLOAD16(g, l) __builtin_amdgcn_global_load_lds(                      \
        (const __attribute__((address_space(1))) void*)(g),                  \
        (__attribute__((address_space(3))) void*)(l), 16, 0, 0)
#define SBAR()   __builtin_amdgcn_s_barrier()
#define SCHED0() __builtin_amdgcn_sched_barrier(0)
#define PRIO(x)  __builtin_amdgcn_s_setprio(x)
#define WAITVM(N) asm volatile("s_waitcnt vmcnt(" #N ")" ::: "memory")
#define LGKM0()  asm volatile("s_waitcnt lgkmcnt(0)" ::: "memory")

// LDS swizzle (verified conflicts==0): (row r, 16B-chunk c) at byte
//   r*64 + (c ^ ((r>>1)&3))*16;  staging pre-inverse-swizzles the global src.
// Schedule: round-7/9 proven form — single SBAR between reads|stage and MFMA,
// counted vmcnt only at tile boundary.

// ===========================================================================
// gemm256: plain bf16 GEMM, 256x256 tile, BK=32, 512 thr, 4 LDS bufs,
// counted-vmcnt pipeline. EPI: 0 = bf16 C, 1 = f32 C,
// 3 = fused scan-out: Cf = acc + bf2f(zin) + Pv[row]*carry[chunk,col].
// ===========================================================================
template<int EPI>
__global__ __launch_bounds__(512) void gemm256(const u16* __restrict__ A1,
                                               const u16* __restrict__ W1,
                                               float* __restrict__ Cf,
                                               u16* __restrict__ Cb,
                                               const u16* __restrict__ zin,
                                               const float* __restrict__ Pv,
                                               const float* __restrict__ carry) {
    constexpr int NT = 32;
    __shared__ u16 lds[4 * 16384];
    const int tid = threadIdx.x;
    const int lane = tid & 63, wid = tid >> 6;
    const int wm = wid >> 2, wn = wid & 3;
    const int fr = lane & 15, fq = lane >> 4;
    const int row0 = blockIdx.x * 256, col0 = blockIdx.y * 256;
    const int r0s = tid >> 2, c0s = tid & 3;

    int offA[8], offB[4];
#pragma unroll
    for (int i = 0; i < 8; ++i) {
        const int r = wm * 128 + i * 16 + fr;
        offA[i] = r * 64 + ((fq ^ ((r >> 1) & 3)) << 4);
    }
#pragma unroll
    for (int j = 0; j < 4; ++j) {
        const int r = wn * 64 + j * 16 + fr;
        offB[j] = r * 64 + ((fq ^ ((r >> 1) & 3)) << 4);
    }

    auto stageA = [&](int s) {
        const int k0 = s * 32;
        char* dst = (char*)lds + (s & 3) * 32768;
#pragma unroll
        for (int j = 0; j < 2; ++j) {
            const int r = j * 128 + r0s;
            const int c = c0s ^ ((r >> 1) & 3);
            GLOAD16(A1 + (size_t)(row0 + r) * D_DIM + k0 + c * 8,
                    dst + j * 8192 + tid * 16);
        }
    };
    auto stageB = [&](int s) {
        const int k0 = s * 32;
        char* dst = (char*)lds + (s & 3) * 32768 + 16384;
#pragma unroll
        for (int j = 0; j < 2; ++j) {
            const int r = j * 128 + r0s;
            const int c = c0s ^ ((r >> 1) & 3);
            GLOAD16(W1 + (size_t)(col0 + r) * D_DIM + k0 + c * 8,
                    dst + j * 8192 + tid * 16);
        }
    };

    f32x4 acc[8][4];
#pragma unroll
    for (int i = 0; i < 8; ++i)
#pragma unroll
        for (int j = 0; j < 4; ++j) acc[i][j] = (f32x4){0.f, 0.f, 0.f, 0.f};

    stageA(0); stageB(0); stageA(1); stageB(1); stageA(2); stageB(2);
    WAITVM(8); SBAR(); SCHED0();

    for (int t = 0; t < NT; ++t) {
        const char* buf  = (const char*)lds + (t & 3) * 32768;
        const char* bufB = buf + 16384;
        short8 af[8], bf[4];
#pragma unroll
        for (int i = 0; i < 4; ++i) af[i] = *(const short8*)(buf + offA[i]);
#pragma unroll
        for (int j = 0; j < 4; ++j) bf[j] = *(const short8*)(bufB + offB[j]);
        if (t + 3 < NT) stageA(t + 3);
        SBAR();
        PRIO(1);
#pragma unroll
        for (int i = 0; i < 4; ++i)
#pragma unroll
            for (int j = 0; j < 4; ++j)
                acc[i][j] = __builtin_amdgcn_mfma_f32_16x16x32_bf16(af[i], bf[j], acc[i][j], 0, 0, 0);
        PRIO(0);
#pragma unroll
        for (int i = 4; i < 8; ++i) af[i] = *(const short8*)(buf + offA[i]);
        if (t + 3 < NT) stageB(t + 3);
        SBAR();
        PRIO(1);
#pragma unroll
        for (int i = 4; i < 8; ++i)
#pragma unroll
            for (int j = 0; j < 4; ++j)
                acc[i][j] = __builtin_amdgcn_mfma_f32_16x16x32_bf16(af[i], bf[j], acc[i][j], 0, 0, 0);
        PRIO(0);
        if (t + 1 < NT) {
            if (t + 3 < NT)      { WAITVM(8); }
            else if (t + 2 < NT) { WAITVM(4); }
            else                 { WAITVM(0); }
            SBAR(); SCHED0();
        }
    }

#pragma unroll
    for (int i = 0; i < 8; ++i)
#pragma unroll
        for (int j = 0; j < 4; ++j) {
            const int r0 = row0 + wm * 128 + i * 16 + fq * 4;
            const int c  = col0 + wn * 64 + j * 16 + fr;
#pragma unroll
            for (int rr = 0; rr < 4; ++rr) {
                if (EPI == 0) Cb[(size_t)(r0 + rr) * D_DIM + c] = f2bf(acc[i][j][rr]);
                else if (EPI == 1) Cf[(size_t)(r0 + rr) * D_DIM + c] = acc[i][j][rr];
                else {
                    const int r = r0 + rr;
                    const float pl = Pv[r];
                    const float cv = carry[(size_t)(r >> 9) * D_DIM + c];
                    const float zv = bf2f(zin[(size_t)r * D_DIM + c]);
                    Cf[(size_t)r * D_DIM + c] = acc[i][j][rr] + fmaf(pl, cv, zv);
                }
            }
        }
}

// ===========================================================================
// gemm_x3: split-precision GEMM (Ah@Wh + Ah@Wl + Al@Wh), 128x256 tile, BK=32,
// 512 thr, 3 bufs, vmcnt(6). EPI: 0 hi/lo bf16 out, 1 f32 out,
// 2 fused router-dot partials via LDS redistribution.
// XF32: A comes from f32 Xf directly — reg-stage 2×float4/thread for tile
// t+2 at the stage slot, split hi/lo + ds_write at the t->t+1 boundary
// (after the counted WAITVM(6); per-tile VMEM op count unchanged at 6).
// ===========================================================================
template<int EPI, bool XF32>
__global__ __launch_bounds__(512) void gemm_x3(const u16* __restrict__ Ah,
                                               const u16* __restrict__ Al,
                                               const float* __restrict__ Xf,
                                               const u16* __restrict__ Wh,
                                               const u16* __restrict__ Wl,
                                               float* __restrict__ Cf,
                                               u16* __restrict__ Chi,
                                               u16* __restrict__ Clo,
                                               const u16* __restrict__ Eh,
                                               const u16* __restrict__ El,
                                               float* __restrict__ Pd) {
    constexpr int NT = 32;
    __shared__ u16 lds[3 * 24576];           // 147456 B; reused as lt[] in EPI=2
    const int tid = threadIdx.x;
    const int lane = tid & 63, wid = tid >> 6;
    const int wm = wid >> 2, wn = wid & 3;
    const int fr = lane & 15, fq = lane >> 4;
    const int row0 = blockIdx.x * 128, col0 = blockIdx.y * 256;
    const int r0s = tid >> 2, c0s = tid & 3;
    const int cS  = c0s ^ ((r0s >> 1) & 3);  // pre-inverse-swizzled k-chunk

    int offA[4], offB[4];
#pragma unroll
    for (int i = 0; i < 4; ++i) {
        const int r = wm * 64 + i * 16 + fr;
        offA[i] = r * 64 + ((fq ^ ((r >> 1) & 3)) << 4);
    }
#pragma unroll
    for (int j = 0; j < 4; ++j) {
        const int r = wn * 64 + j * 16 + fr;
        offB[j] = r * 64 + ((fq ^ ((r >> 1) & 3)) << 4);
    }

    auto stageAhl = [&](int s) {             // bf16-plane path
        char* base = (char*)lds + (s % 3) * 49152;
        const size_t g = (size_t)(row0 + r0s) * D_DIM + s * 32 + cS * 8;
        GLOAD16(Ah + g, base + tid * 16);
        GLOAD16(Al + g, base + 8192 + tid * 16);
    };
    auto stageBh = [&](int s) {
        char* base = (char*)lds + (s % 3) * 49152 + 16384;
#pragma unroll
        for (int j = 0; j < 2; ++j) {
            const int r = j * 128 + r0s;
            const int c = c0s ^ ((r >> 1) & 3);
            GLOAD16(Wh + (size_t)(col0 + r) * D_DIM + s * 32 + c * 8,
                    base + j * 8192 + tid * 16);
        }
    };
    auto stageBl = [&](int s) {
        char* base = (char*)lds + (s % 3) * 49152 + 32768;
#pragma unroll
        for (int j = 0; j < 2; ++j) {
            const int r = j * 128 + r0s;
            const int c = c0s ^ ((r >> 1) & 3);
            GLOAD16(Wl + (size_t)(col0 + r) * D_DIM + s * 32 + c * 8,
                    base + j * 8192 + tid * 16);
        }
    };

    // XF32 register staging: two named sets, parity = target-tile & 1.
    float4 xA0, xA1, xB0, xB1;
    auto xf_addr = [&](int s) {
        return Xf + (size_t)(row0 + r0s) * D_DIM + s * 32 + cS * 8;
    };
    auto xf_write = [&](int T) {             // split + publish x(T) into buf T%3
        const float4 v0 = (T & 1) ? xB0 : xA0;
        const float4 v1 = (T & 1) ? xB1 : xA1;
        char* base = (char*)lds + (T % 3) * 49152;
        short8 hv, lv;
        const float f[8] = {v0.x, v0.y, v0.z, v0.w, v1.x, v1.y, v1.z, v1.w};
#pragma unroll
        for (int j = 0; j < 8; ++j) {
            const u16 h = f2bf(f[j]);
            hv[j] = (short)h;
            lv[j] = (short)f2bf(f[j] - bf2f(h));
        }
        *(short8*)(base + tid * 16)        = hv;
        *(short8*)(base + 8192 + tid * 16) = lv;
    };

    f32x4 acc[4][4];
#pragma unroll
    for (int i = 0; i < 4; ++i)
#pragma unroll
        for (int j = 0; j < 4; ++j) acc[i][j] = (f32x4){0.f, 0.f, 0.f, 0.f};

    // prologue (issue order fixes vmcnt positions: A/x(0), B(0), A/x(1), B(1))
    if (XF32) { const float* p = xf_addr(0); xA0 = *(const float4*)p; xA1 = *(const float4*)(p + 4); }
    else stageAhl(0);
    stageBh(0); stageBl(0);
    if (XF32) { const float* p = xf_addr(1); xB0 = *(const float4*)p; xB1 = *(const float4*)(p + 4); }
    else stageAhl(1);
    stageBh(1); stageBl(1);
    WAITVM(6);
    if (XF32) { xf_write(0); LGKM0(); }
    SBAR(); SCHED0();

    for (int t = 0; t < NT; ++t) {
        const char* base = (const char*)lds + (t % 3) * 49152;
        short8 afh[4], afl[4], bfh[4], bfl[4];
        // ---- phase 0: hi*hi
#pragma unroll
        for (int i = 0; i < 4; ++i) afh[i] = *(const short8*)(base + offA[i]);
#pragma unroll
        for (int j = 0; j < 4; ++j) bfh[j] = *(const short8*)(base + 16384 + offB[j]);
        if (t + 2 < NT) stageBh(t + 2);
        SBAR();
        PRIO(1);
#pragma unroll
        for (int i = 0; i < 4; ++i)
#pragma unroll
            for (int j = 0; j < 4; ++j)
                acc[i][j] = __builtin_amdgcn_mfma_f32_16x16x32_bf16(afh[i], bfh[j], acc[i][j], 0, 0, 0);
        PRIO(0);
        // ---- phase 1: hi*lo
#pragma unroll
        for (int j = 0; j < 4; ++j) bfl[j] = *(const short8*)(base + 32768 + offB[j]);
        if (t + 2 < NT) stageBl(t + 2);
        SBAR();
        PRIO(1);
#pragma unroll
        for (int i = 0; i < 4; ++i)
#pragma unroll
            for (int j = 0; j < 4; ++j)
                acc[i][j] = __builtin_amdgcn_mfma_f32_16x16x32_bf16(afh[i], bfl[j], acc[i][j], 0, 0, 0);
        PRIO(0);
        // ---- phase 2: lo*hi (+ issue next A)
#pragma unroll
        for (int i = 0; i < 4; ++i) afl[i] = *(const short8*)(base + 8192 + offA[i]);
        if (t + 2 < NT) {
            if (XF32) {
                const float* p = xf_addr(t + 2);
                if (((t + 2) & 1) == 0) { xA0 = *(const float4*)p; xA1 = *(const float4*)(p + 4); }
                else                    { xB0 = *(const float4*)p; xB1 = *(const float4*)(p + 4); }
            } else stageAhl(t + 2);
        }
        SBAR();
        PRIO(1);
#pragma unroll
        for (int i = 0; i < 4; ++i)
#pragma unroll
            for (int j = 0; j < 4; ++j)
                acc[i][j] = __builtin_amdgcn_mfma_f32_16x16x32_bf16(afl[i], bfh[j], acc[i][j], 0, 0, 0);
        PRIO(0);
        // ---- tile boundary
        if (t + 1 < NT) {
            if (t + 2 < NT) { WAITVM(6); }
            else            { WAITVM(0); }
            if (XF32) { xf_write(t + 1); LGKM0(); }
            SBAR(); SCHED0();
        }
    }

    if (EPI == 2) {
        // redistribute t through LDS (staging bufs dead), then coalesced E reads
        __syncthreads();
        float* lt = (float*)lds;             // [128][260] = 133120 B
#pragma unroll
        for (int i = 0; i < 4; ++i)
#pragma unroll
            for (int j = 0; j < 4; ++j) {
                const int rl = wm * 64 + i * 16 + fq * 4;
                const int cl = wn * 64 + j * 16 + fr;
#pragma unroll
                for (int rr = 0; rr < 4; ++rr)
                    lt[(rl + rr) * 260 + cl] = acc[i][j][rr];
            }
        __syncthreads();
        const int row = tid >> 2, q = tid & 3;
        const int rg  = row0 + row;
        float s = 0.f;
        if (rg > 0) {
            const u16* ehp = Eh + (size_t)(rg - 1) * D_DIM + col0 + q * 64;
            const u16* elp = El + (size_t)(rg - 1) * D_DIM + col0 + q * 64;
            const float* ltp = lt + row * 260 + q * 64;
#pragma unroll
            for (int k8 = 0; k8 < 8; ++k8) {
                short8 hv = *(const short8*)(ehp + k8 * 8);
                short8 lv = *(const short8*)(elp + k8 * 8);
#pragma unroll
                for (int e = 0; e < 8; ++e) {
                    const float ev = bf2f((u16)hv[e]) + bf2f((u16)lv[e]);
                    s = fmaf(ltp[k8 * 8 + e], ev, s);
                }
            }
        }
        Pd[(size_t)(blockIdx.y * 4 + q) * (gridDim.x * 128) + rg] = s;
        return;
    }
#pragma unroll
    for (int i = 0; i < 4; ++i)
#pragma unroll
        for (int j = 0; j < 4; ++j) {
            const int r0 = row0 + wm * 64 + i * 16 + fq * 4;
            const int c  = col0 + wn * 64 + j * 16 + fr;
#pragma unroll
            for (int rr = 0; rr < 4; ++rr) {
                const float v = acc[i][j][rr];
                if (EPI == 0) {
                    const u16 h = f2bf(v);
                    Chi[(size_t)(r0 + rr) * D_DIM + c] = h;
                    Clo[(size_t)(r0 + rr) * D_DIM + c] = f2bf(v - bf2f(h));
                } else {
                    Cf[(size_t)(r0 + rr) * D_DIM + c] = v;
                }
            }
        }
}

// ===========================================================================
// norm2: fused dual-norm GEMM (round-7 form).
// ===========================================================================
__global__ __launch_bounds__(512) void norm2(const u16* __restrict__ A,
                                             const u16* __restrict__ Bq,
                                             const u16* __restrict__ Bk,
                                             float* __restrict__ Pq,
                                             float* __restrict__ Pk) {
    constexpr int NT = 32;
    __shared__ u16 lds[3 * 20480];
    const int tid = threadIdx.x;
    const int lane = tid & 63, wid = tid >> 6;
    const int wm = wid >> 2, wn = wid & 3;
    const int fr = lane & 15, fq = lane >> 4;
    const int row0 = blockIdx.x * 128, col0 = blockIdx.y * 256;
    const int r0s = tid >> 2, c0s = tid & 3;

    int offA[4], offB[4];
#pragma unroll
    for (int i = 0; i < 4; ++i) {
        const int r = wm * 64 + i * 16 + fr;
        offA[i] = r * 64 + ((fq ^ ((r >> 1) & 3)) << 4);
    }
#pragma unroll
    for (int j = 0; j < 4; ++j) {
        const int r = wn * 64 + j * 16 + fr;
        offB[j] = r * 64 + ((fq ^ ((r >> 1) & 3)) << 4);
    }

    auto stageA = [&](int s) {
        char* base = (char*)lds + (s % 3) * 40960;
        const int r = r0s;
        const int c = c0s ^ ((r >> 1) & 3);
        GLOAD16(A + (size_t)(row0 + r) * D_DIM + s * 32 + c * 8, base + tid * 16);
    };
    auto stageBq = [&](int s) {
        char* base = (char*)lds + (s % 3) * 40960 + 8192;
#pragma unroll
        for (int j = 0; j < 2; ++j) {
            const int r = j * 128 + r0s;
            const int c = c0s ^ ((r >> 1) & 3);
            GLOAD16(Bq + (size_t)(col0 + r) * D_DIM + s * 32 + c * 8,
                    base + j * 8192 + tid * 16);
        }
    };
    auto stageBk = [&](int s) {
        char* base = (char*)lds + (s % 3) * 40960 + 24576;
#pragma unroll
        for (int j = 0; j < 2; ++j) {
            const int r = j * 128 + r0s;
            const int c = c0s ^ ((r >> 1) & 3);
            GLOAD16(Bk + (size_t)(col0 + r) * D_DIM + s * 32 + c * 8,
                    base + j * 8192 + tid * 16);
        }
    };

    f32x4 accq[4][4], acck[4][4];
#pragma unroll
    for (int i = 0; i < 4; ++i)
#pragma unroll
        for (int j = 0; j < 4; ++j) {
            accq[i][j] = (f32x4){0.f, 0.f, 0.f, 0.f};
            acck[i][j] = (f32x4){0.f, 0.f, 0.f, 0.f};
        }

    stageA(0); stageBq(0); stageBk(0);
    stageA(1); stageBq(1); stageBk(1);
    WAITVM(5); SBAR(); SCHED0();

    for (int t = 0; t < NT; ++t) {
        const char* base = (const char*)lds + (t % 3) * 40960;
        short8 af[4], bq[4], bk[4];
#pragma unroll
        for (int i = 0; i < 4; ++i) af[i] = *(const short8*)(base + offA[i]);
#pragma unroll
        for (int j = 0; j < 4; ++j) bq[j] = *(const short8*)(base + 8192 + offB[j]);
        if (t + 2 < NT) { stageA(t + 2); stageBq(t + 2); }
        SBAR();
        PRIO(1);
#pragma unroll
        for (int i = 0; i < 4; ++i)
#pragma unroll
            for (int j = 0; j < 4; ++j)
                accq[i][j] = __builtin_amdgcn_mfma_f32_16x16x32_bf16(af[i], bq[j], accq[i][j], 0, 0, 0);
        PRIO(0);
#pragma unroll
        for (int j = 0; j < 4; ++j) bk[j] = *(const short8*)(base + 24576 + offB[j]);
        if (t + 2 < NT) stageBk(t + 2);
        SBAR();
        PRIO(1);
#pragma unroll
        for (int i = 0; i < 4; ++i)
#pragma unroll
            for (int j = 0; j < 4; ++j)
                acck[i][j] = __builtin_amdgcn_mfma_f32_16x16x32_bf16(af[i], bk[j], acck[i][j], 0, 0, 0);
        PRIO(0);
        if (t + 1 < NT) {
            if (t + 2 < NT) { WAITVM(5); }
            else            { WAITVM(0); }
            SBAR(); SCHED0();
        }
    }

    const int Ltot = gridDim.x * 128;
#pragma unroll
    for (int i = 0; i < 4; ++i)
#pragma unroll
        for (int rr = 0; rr < 4; ++rr) {
            const int r = row0 + wm * 64 + i * 16 + fq * 4 + rr;
            float sq = 0.f, sk = 0.f;
#pragma unroll
            for (int j = 0; j < 4; ++j) {
                sq += accq[i][j][rr] * accq[i][j][rr];
                sk += acck[i][j][rr] * acck[i][j][rr];
            }
#pragma unroll
            for (int off = 1; off < 16; off <<= 1) {
                sq += __shfl_xor(sq, off);
                sk += __shfl_xor(sk, off);
            }
            if (fr == 0) {
                Pq[(size_t)(blockIdx.y * 4 + wn) * Ltot + r] = sq;
                Pk[(size_t)(blockIdx.y * 4 + wn) * Ltot + r] = sk;
            }
        }
}

// ---------------------------------------------------------------------------
// gemm_dd2: dual D x D bf16 GEMM (z=0: A@W0^T -> C0, z=1: A@W1^T -> C1).
// ---------------------------------------------------------------------------
__global__ __launch_bounds__(256) void gemm_dd2(const u16* __restrict__ A,
                                                const u16* __restrict__ W0,
                                                const u16* __restrict__ W1,
                                                u16* __restrict__ C0,
                                                u16* __restrict__ C1) {
    __shared__ u16 lA[128 * 32];
    __shared__ u16 lB[128 * 32];
    const u16* W = blockIdx.z ? W1 : W0;
    u16* Cbf     = blockIdx.z ? C1 : C0;
    const int tid  = threadIdx.x;
    const int lane = tid & 63, wid = tid >> 6;
    const int wy = wid & 1, wx = wid >> 1;
    const int fr = lane & 15, fq = lane >> 4;
    const int row0 = blockIdx.x * 128;
    const int col0 = blockIdx.y * 128;

    const int rS   = tid >> 2;
    const int subS = (tid & 3) ^ ((rS >> 1) & 3);
    const u16* gA = A + (size_t)(row0 + rS) * D_DIM + subS * 8;
    const u16* gB = W + (size_t)(col0 + rS) * D_DIM + subS * 8;
    char* lA0 = (char*)lA + tid * 16;
    char* lB0 = (char*)lB + tid * 16;
    const size_t rowStep = (size_t)64 * D_DIM;

    int offA[4], offB[4];
#pragma unroll
    for (int i = 0; i < 4; ++i) {
        const int ra = wy * 64 + i * 16 + fr;
        const int rb = wx * 64 + i * 16 + fr;
        offA[i] = ra * 64 + ((fq ^ ((ra >> 1) & 3)) << 4);
        offB[i] = rb * 64 + ((fq ^ ((rb >> 1) & 3)) << 4);
    }

    f32x4 acc[4][4];
#pragma unroll
    for (int i = 0; i < 4; ++i)
#pragma unroll
        for (int j = 0; j < 4; ++j) acc[i][j] = (f32x4){0.f, 0.f, 0.f, 0.f};

    for (int k0 = 0; k0 < D_DIM; k0 += 32) {
        __syncthreads();
        GLOAD16(gA + k0, lA0);
        GLOAD16(gA + k0 + rowStep, lA0 + 4096);
        GLOAD16(gB + k0, lB0);
        GLOAD16(gB + k0 + rowStep, lB0 + 4096);
        __syncthreads();
        short8 af[4], bf[4];
#pragma unroll
        for (int i = 0; i < 4; ++i) af[i] = *(const short8*)((const char*)lA + offA[i]);
#pragma unroll
        for (int j = 0; j < 4; ++j) bf[j] = *(const short8*)((const char*)lB + offB[j]);
#pragma unroll
        for (int i = 0; i < 4; ++i)
#pragma unroll
            for (int j = 0; j < 4; ++j)
                acc[i][j] = __builtin_amdgcn_mfma_f32_16x16x32_bf16(af[i], bf[j], acc[i][j], 0, 0, 0);
    }
#pragma unroll
    for (int i = 0; i < 4; ++i)
#pragma unroll
        for (int j = 0; j < 4; ++j) {
            const int r0 = row0 + wy * 64 + i * 16 + fq * 4;
            const int c  = col0 + wx * 64 + j * 16 + fr;
#pragma unroll
            for (int r = 0; r < 4; ++r)
                Cbf[(size_t)(r0 + r) * D_DIM + c] = f2bf(acc[i][j][r]);
        }
}

// ===========================================================================
// prep_all: all weight preprocessing in one dispatch. grid (32,32,8), 256 thr.
// ===========================================================================
__global__ __launch_bounds__(256) void prep_all(const float* __restrict__ Wq,
                                                const float* __restrict__ Wk,
                                                const float* __restrict__ Wr,
                                                const float* __restrict__ We,
                                                const float* __restrict__ Wm,
                                                const float* __restrict__ Wd,
                                                u16* __restrict__ WqTh, u16* __restrict__ WqTl,
                                                u16* __restrict__ WkTh, u16* __restrict__ WkTl,
                                                u16* __restrict__ WmTb, u16* __restrict__ WrTb,
                                                u16* __restrict__ Wqb, u16* __restrict__ Wkb,
                                                u16* __restrict__ Wdb,
                                                u16* __restrict__ Weh, u16* __restrict__ Wel) {
    const int task = blockIdx.z;
    if (task < 4) {
        __shared__ float tile[32][33];
        const float* W = (task == 0) ? Wq : (task == 1) ? Wk : (task == 2) ? Wm : Wr;
        u16* Th = (task == 0) ? WqTh : (task == 1) ? WkTh : (task == 2) ? WmTb : WrTb;
        u16* Tl = (task == 0) ? WqTl : (task == 1) ? WkTl : nullptr;
        const int e0 = blockIdx.x * 32, d0 = blockIdx.y * 32;
        const int tx = threadIdx.x & 31, ty = threadIdx.x >> 5;
#pragma unroll
        for (int i = 0; i < 32; i += 8)
            tile[ty + i][tx] = W[(size_t)(e0 + ty + i) * D_DIM + d0 + tx];
        __syncthreads();
#pragma unroll
        for (int i = 0; i < 32; i += 8) {
            float v = tile[tx][ty + i];
            u16 h = f2bf(v);
            Th[(size_t)(d0 + ty + i) * D_DIM + e0 + tx] = h;
            if (Tl) Tl[(size_t)(d0 + ty + i) * D_DIM + e0 + tx] = f2bf(v - bf2f(h));
        }
    } else {
        const int idx = (blockIdx.y * 32 + blockIdx.x) * 256 + threadIdx.x;  // < 262144
        if (task == 7) {
            float4 v = ((const float4*)We)[idx];
            ushort4 h, l;
            h.x = f2bf(v.x); l.x = f2bf(v.x - bf2f(h.x));
            h.y = f2bf(v.y); l.y = f2bf(v.y - bf2f(h.y));
            h.z = f2bf(v.z); l.z = f2bf(v.z - bf2f(h.z));
            h.w = f2bf(v.w); l.w = f2bf(v.w - bf2f(h.w));
            ((ushort4*)Weh)[idx] = h;
            ((ushort4*)Wel)[idx] = l;
        } else {
            const float* S = (task == 4) ? Wq : (task == 5) ? Wk : Wd;
            u16* D = (task == 4) ? Wqb : (task == 5) ? Wkb : Wdb;
            float4 v = ((const float4*)S)[idx];
            ushort4 o = {f2bf(v.x), f2bf(v.y), f2bf(v.z), f2bf(v.w)};
            ((ushort4*)D)[idx] = o;
        }
    }
}

// ---------------------------------------------------------------------------
// small kernels
// ---------------------------------------------------------------------------
__global__ void split_bf16(const float* __restrict__ src, u16* __restrict__ hi,
                           u16* __restrict__ lo, int n4) {
    int i = blockIdx.x * 256 + threadIdx.x;
    if (i >= n4) return;
    float4 v = ((const float4*)src)[i];
    ushort4 h, l;
    h.x = f2bf(v.x); l.x = f2bf(v.x - bf2f(h.x));
    h.y = f2bf(v.y); l.y = f2bf(v.y - bf2f(h.y));
    h.z = f2bf(v.z); l.z = f2bf(v.z - bf2f(h.z));
    h.w = f2bf(v.w); l.w = f2bf(v.w - bf2f(h.w));
    ((ushort4*)hi)[i] = h;
    ((ushort4*)lo)[i] = l;
}

// combine fused-router partials -> p -> gates a, bs
__global__ void combine_router(const float* __restrict__ pd,
                               const float* __restrict__ pq,
                               const float* __restrict__ pk,
                               const int* __restrict__ cu, int nseq,
                               float* __restrict__ a, float* __restrict__ bs,
                               int L) {
    int l = blockIdx.x * 256 + threadIdx.x;
    if (l >= L) return;
    float dot = 0.f, q2 = 0.f, k2 = 0.f;
#pragma unroll
    for (int j = 0; j < 16; ++j) {
        dot += pd[(size_t)j * L + l];
        k2  += pk[(size_t)j * L + l];
        if (l > 0) q2 += pq[(size_t)j * L + l - 1];
    }
    float pv;
    if (l == 0) pv = 1.f;
    else {
        float dn = fmaxf(sqrtf(q2), 1e-12f) * fmaxf(sqrtf(k2), 1e-12f);
        pv = 0.5f * (1.f - dot / dn);
    }
    bool start = false;
    for (int s = 0; s < nseq; ++s) start = start || (cu[s] == l);
    if (start) pv = 1.f;
    bool mask = pv > 0.5f;
    float pc  = fminf(fmaxf(pv, 1e-4f), 1.f - 1e-4f);
    a[l]  = start ? 0.f : (mask ? (1.f - pc) : 1.f);
    bs[l] = mask ? pc : 0.f;
}

// ---------------------------------------------------------------------------
// scan (bf16 z storage, f32 running state)
// ---------------------------------------------------------------------------
__global__ __launch_bounds__(256) void scan_local(const float* __restrict__ a,
                                                  const float* __restrict__ bs,
                                                  u16* __restrict__ m,
                                                  float* __restrict__ P) {
    __shared__ float a_s[CL], b_s[CL];
    const int chunk = blockIdx.x;
    const int d     = blockIdx.y * 256 + threadIdx.x;
    const int l0    = chunk * CL;
    for (int i = threadIdx.x; i < CL; i += 256) { a_s[i] = a[l0 + i]; b_s[i] = bs[l0 + i]; }
    __syncthreads();
    if (blockIdx.y == 0 && threadIdx.x == 0) {
        float pp = 1.f;
        for (int i = 0; i < CL; ++i) { pp *= a_s[i]; P[l0 + i] = pp; }
    }
    float h = 0.f;
    u16* mp = m + (size_t)l0 * D_DIM + d;
    for (int i = 0; i < CL; ++i) {
        float mv = bf2f(mp[(size_t)i * D_DIM]);
        h = fmaf(a_s[i], h, b_s[i] * mv);
        mp[(size_t)i * D_DIM] = f2bf(h);
    }
}

__global__ void scan_carry(const u16* __restrict__ y, const float* __restrict__ P,
                           float* __restrict__ carry, int nchunks) {
    const int d = blockIdx.x * 256 + threadIdx.x;
    float H = 0.f;
    for (int c = 0; c < nchunks; ++c) {
        carry[(size_t)c * D_DIM + d] = H;
        const float Ac = P[c * CL + (CL - 1)];
        const float Bc = bf2f(y[((size_t)c * CL + (CL - 1)) * D_DIM + d]);
        H = fmaf(Ac, H, Bc);
    }
}

// ---------------------------------------------------------------------------
extern "C" void kernel_launch(void* const* d_in, const int* in_sizes, int n_in,
                              void* d_out, int out_size, void* d_ws, size_t ws_size,
                              hipStream_t stream) {
    const float* x  = (const float*)d_in[0];
    const float* Wq = (const float*)d_in[1];
    const float* Wk = (const float*)d_in[2];
    const float* Wr = (const float*)d_in[3];
    const float* We = (const float*)d_in[4];
    const float* Wm = (const float*)d_in[5];
    const float* Wd = (const float*)d_in[6];
    const int*   cu = (const int*)d_in[7];
    const int L    = in_sizes[0] / D_DIM;      // 32768
    const int nseq = in_sizes[7] - 1;          // 4

    const size_t LD2 = (size_t)L * D_DIM * 2;  // 64 MiB bf16 plane
    const int nDD4 = (int)((size_t)D_DIM * D_DIM / 4);
    const int nchunks = L / CL;

    // ws: R1a z | R1b {Wdmb,Wdrb} | R2a enc_hi | R2b enc_lo | scalars
    char* ws = (char*)d_ws;
    u16*   zbuf = (u16*)ws;
    u16*   Wdmb = (u16*)(ws + LD2);
    u16*   Wdrb = (u16*)(ws + LD2 + (2u << 20));
    u16*   ench = (u16*)(ws + 2 * LD2);
    u16*   encl = (u16*)(ws + 3 * LD2);
    float* av   = (float*)(ws + 4 * LD2);
    float* bs   = av + L;
    float* P    = bs + L;
    float* carry= P  + L;                      // [nchunks, D] = 256 KB

    // d_out scratch (ALL dead before the final gemm256<3> writes out):
    char* dob = (char*)d_out;
    u16* Weh   = (u16*)dob;
    u16* Wel   = (u16*)(dob + (2u << 20));
    u16* WqTh  = (u16*)(dob + (4u << 20));
    u16* WqTl  = (u16*)(dob + (6u << 20));
    u16* WkTh  = (u16*)(dob + (8u << 20));
    u16* WkTl  = (u16*)(dob + (10u << 20));
    float* Mf  = (float*)(dob + (12u << 20));
    u16* Mh    = (u16*)(dob + (16u << 20));
    u16* Ml    = (u16*)(dob + (18u << 20));
    u16* Wqb   = (u16*)(dob + (20u << 20));
    u16* Wkb   = (u16*)(dob + (22u << 20));
    u16* Wdb   = (u16*)(dob + (24u << 20));
    u16* WmTb  = (u16*)(dob + (26u << 20));
    u16* WrTb  = (u16*)(dob + (28u << 20));
    float* partdot = (float*)(dob + (34u << 20));   // [16][L] = 2 MB
    float* partnq  = (float*)(dob + (36u << 20));
    float* partnk  = (float*)(dob + (38u << 20));
    float* out = (float*)d_out;

    dim3 gX3L(L / 128, D_DIM / 256);           // (256, 4)
    dim3 gX3D(D_DIM / 128, D_DIM / 256);       // (8, 4)
    dim3 g256(L / 256, D_DIM / 256);           // (128, 4)
    dim3 gDD2(D_DIM / 128, D_DIM / 128, 2);    // (8, 8, 2)
    dim3 gPrep(32, 32, 8);

    // 1. all weight prep in one dispatch
    prep_all<<<gPrep, 256, 0, stream>>>(Wq, Wk, Wr, We, Wm, Wd,
                                        WqTh, WqTl, WkTh, WkTl, WmTb, WrTb,
                                        Wqb, Wkb, Wdb, Weh, Wel);
    // 2. enc (x3, direct f32-x staging) -> hi/lo planes
    gemm_x3<0, true><<<gX3L, 512, 0, stream>>>(nullptr, nullptr, x, Weh, Wel,
                                               nullptr, ench, encl,
                                               nullptr, nullptr, nullptr);
    // 3. Wdm = Wd@Wm, Wdr = Wd@Wr (dual dispatch)
    gemm_dd2<<<gDD2, 256, 0, stream>>>(Wdb, WmTb, WrTb, Wdmb, Wdrb);
    // 4. M = Wq^T @ Wk (x3) + split
    gemm_x3<1, false><<<gX3D, 512, 0, stream>>>(WqTh, WqTl, nullptr, WkTh, WkTl,
                                                Mf, nullptr, nullptr,
                                                nullptr, nullptr, nullptr);
    split_bf16<<<(nDD4 + 255) / 256, 256, 0, stream>>>(Mf, Mh, Ml, nDD4);
    // 5. fused t-GEMM + router dot partials (LDS-redistributed epilogue)
    gemm_x3<2, false><<<gX3L, 512, 0, stream>>>(ench, encl, nullptr, Mh, Ml,
                                                nullptr, nullptr, nullptr,
                                                ench, encl, partdot);
    // 6. fused q,k norm partials
    norm2<<<gX3L, 512, 0, stream>>>(ench, Wqb, Wkb, partnq, partnk);
    // 7. combine partials -> p -> gates
    combine_router<<<(L + 255) / 256, 256, 0, stream>>>(partdot, partnq, partnk,
                                                        cu, nseq, av, bs, L);
    // 8. z = enc @ Wdm^T (bf16)
    gemm256<0><<<g256, 512, 0, stream>>>(ench, Wdmb, nullptr, zbuf,
                                         nullptr, nullptr, nullptr);
    // 9. scan over z (decode-commuted)
    dim3 gsl(nchunks, D_DIM / 256);
    scan_local<<<gsl, 256, 0, stream>>>(av, bs, zbuf, P);
    scan_carry<<<D_DIM / 256, 256, 0, stream>>>(zbuf, P, carry, nchunks);
    // 10. out = enc @ Wdr^T + z_scanned + P*carry  (fused epilogue, f32 out)
    gemm256<3><<<g256, 512, 0, stream>>>(ench, Wdrb, out, nullptr,
                                         zbuf, P, carry);
}

// Round 11
// 907.351 us; speedup vs baseline: 1.0156x; 1.0156x over previous
//
#include <hip/hip_runtime.h>
#include <math.h>

#define D_DIM 1024
#define CL 512   // scan chunk length

typedef __attribute__((ext_vector_type(8))) short short8;
typedef __attribute__((ext_vector_type(4))) float f32x4;
typedef unsigned short u16;

__device__ __forceinline__ u16 f2bf(float f) {
    unsigned int u = __float_as_uint(f);
    u += 0x7fff + ((u >> 16) & 1);          // round-to-nearest-even
    return (u16)(u >> 16);
}
__device__ __forceinline__ float bf2f(u16 h) {
    return __uint_as_float((unsigned int)h << 16);
}

#define GLOAD16(g, l) __builtin_amdgcn_global_load_lds(                      \
        (const __attribute__((address_space(1))) void*)(g),                  \
        (__attribute__((address_space(3))) void*)(l), 16, 0, 0)
#define SBAR()   __builtin_amdgcn_s_barrier()
#define SCHED0() __builtin_amdgcn_sched_barrier(0)
#define PRIO(x)  __builtin_amdgcn_s_setprio(x)
#define WAITVM(N) asm volatile("s_waitcnt vmcnt(" #N ")" ::: "memory")

// LDS swizzle (verified conflicts==0): (row r, 16B-chunk c) at byte
//   r*64 + (c ^ ((r>>1)&3))*16;  staging pre-inverse-swizzles the global src.
// Schedule: round-7/9 proven form — single SBAR between reads|stage and MFMA,
// counted vmcnt only at tile boundary.

// ===========================================================================
// gemm256: plain bf16 GEMM, 256x256 tile, BK=32, 512 thr, 4 LDS bufs,
// counted-vmcnt pipeline. EPI: 0 = bf16 C, 1 = f32 C,
// 3 = fused scan-out: Cf = acc + bf2f(zin) + Pv[row]*carry[chunk,col].
// ===========================================================================
template<int EPI>
__global__ __launch_bounds__(512) void gemm256(const u16* __restrict__ A1,
                                               const u16* __restrict__ W1,
                                               float* __restrict__ Cf,
                                               u16* __restrict__ Cb,
                                               const u16* __restrict__ zin,
                                               const float* __restrict__ Pv,
                                               const float* __restrict__ carry) {
    constexpr int NT = 32;
    __shared__ u16 lds[4 * 16384];
    const int tid = threadIdx.x;
    const int lane = tid & 63, wid = tid >> 6;
    const int wm = wid >> 2, wn = wid & 3;
    const int fr = lane & 15, fq = lane >> 4;
    const int row0 = blockIdx.x * 256, col0 = blockIdx.y * 256;
    const int r0s = tid >> 2, c0s = tid & 3;

    int offA[8], offB[4];
#pragma unroll
    for (int i = 0; i < 8; ++i) {
        const int r = wm * 128 + i * 16 + fr;
        offA[i] = r * 64 + ((fq ^ ((r >> 1) & 3)) << 4);
    }
#pragma unroll
    for (int j = 0; j < 4; ++j) {
        const int r = wn * 64 + j * 16 + fr;
        offB[j] = r * 64 + ((fq ^ ((r >> 1) & 3)) << 4);
    }

    auto stageA = [&](int s) {
        const int k0 = s * 32;
        char* dst = (char*)lds + (s & 3) * 32768;
#pragma unroll
        for (int j = 0; j < 2; ++j) {
            const int r = j * 128 + r0s;
            const int c = c0s ^ ((r >> 1) & 3);
            GLOAD16(A1 + (size_t)(row0 + r) * D_DIM + k0 + c * 8,
                    dst + j * 8192 + tid * 16);
        }
    };
    auto stageB = [&](int s) {
        const int k0 = s * 32;
        char* dst = (char*)lds + (s & 3) * 32768 + 16384;
#pragma unroll
        for (int j = 0; j < 2; ++j) {
            const int r = j * 128 + r0s;
            const int c = c0s ^ ((r >> 1) & 3);
            GLOAD16(W1 + (size_t)(col0 + r) * D_DIM + k0 + c * 8,
                    dst + j * 8192 + tid * 16);
        }
    };

    f32x4 acc[8][4];
#pragma unroll
    for (int i = 0; i < 8; ++i)
#pragma unroll
        for (int j = 0; j < 4; ++j) acc[i][j] = (f32x4){0.f, 0.f, 0.f, 0.f};

    stageA(0); stageB(0); stageA(1); stageB(1); stageA(2); stageB(2);
    WAITVM(8); SBAR(); SCHED0();

    for (int t = 0; t < NT; ++t) {
        const char* buf  = (const char*)lds + (t & 3) * 32768;
        const char* bufB = buf + 16384;
        short8 af[8], bf[4];
#pragma unroll
        for (int i = 0; i < 4; ++i) af[i] = *(const short8*)(buf + offA[i]);
#pragma unroll
        for (int j = 0; j < 4; ++j) bf[j] = *(const short8*)(bufB + offB[j]);
        if (t + 3 < NT) stageA(t + 3);
        SBAR();
        PRIO(1);
#pragma unroll
        for (int i = 0; i < 4; ++i)
#pragma unroll
            for (int j = 0; j < 4; ++j)
                acc[i][j] = __builtin_amdgcn_mfma_f32_16x16x32_bf16(af[i], bf[j], acc[i][j], 0, 0, 0);
        PRIO(0);
#pragma unroll
        for (int i = 4; i < 8; ++i) af[i] = *(const short8*)(buf + offA[i]);
        if (t + 3 < NT) stageB(t + 3);
        SBAR();
        PRIO(1);
#pragma unroll
        for (int i = 4; i < 8; ++i)
#pragma unroll
            for (int j = 0; j < 4; ++j)
                acc[i][j] = __builtin_amdgcn_mfma_f32_16x16x32_bf16(af[i], bf[j], acc[i][j], 0, 0, 0);
        PRIO(0);
        if (t + 1 < NT) {
            if (t + 3 < NT)      { WAITVM(8); }
            else if (t + 2 < NT) { WAITVM(4); }
            else                 { WAITVM(0); }
            SBAR(); SCHED0();
        }
    }

#pragma unroll
    for (int i = 0; i < 8; ++i)
#pragma unroll
        for (int j = 0; j < 4; ++j) {
            const int r0 = row0 + wm * 128 + i * 16 + fq * 4;
            const int c  = col0 + wn * 64 + j * 16 + fr;
#pragma unroll
            for (int rr = 0; rr < 4; ++rr) {
                if (EPI == 0) Cb[(size_t)(r0 + rr) * D_DIM + c] = f2bf(acc[i][j][rr]);
                else if (EPI == 1) Cf[(size_t)(r0 + rr) * D_DIM + c] = acc[i][j][rr];
                else {
                    const int r = r0 + rr;
                    const float pl = Pv[r];
                    const float cv = carry[(size_t)(r >> 9) * D_DIM + c];
                    const float zv = bf2f(zin[(size_t)r * D_DIM + c]);
                    Cf[(size_t)r * D_DIM + c] = acc[i][j][rr] + fmaf(pl, cv, zv);
                }
            }
        }
}

// ===========================================================================
// gemm_x3: split-precision GEMM (Ah@Wh + Ah@Wl + Al@Wh), 128x256 tile, BK=32,
// 512 thr, 3 bufs, vmcnt(6). EPI: 0 hi/lo bf16 out, 1 f32 out,
// 2 fused router-dot partials via LDS redistribution (E prefetched to regs
// BEFORE the redistribution barriers so its HBM latency hides there).
// ===========================================================================
template<int EPI>
__global__ __launch_bounds__(512) void gemm_x3(const u16* __restrict__ Ah,
                                               const u16* __restrict__ Al,
                                               const u16* __restrict__ Wh,
                                               const u16* __restrict__ Wl,
                                               float* __restrict__ Cf,
                                               u16* __restrict__ Chi,
                                               u16* __restrict__ Clo,
                                               const u16* __restrict__ Eh,
                                               const u16* __restrict__ El,
                                               float* __restrict__ Pd) {
    constexpr int NT = 32;
    __shared__ u16 lds[3 * 24576];           // 147456 B; reused as lt[] in EPI=2
    const int tid = threadIdx.x;
    const int lane = tid & 63, wid = tid >> 6;
    const int wm = wid >> 2, wn = wid & 3;
    const int fr = lane & 15, fq = lane >> 4;
    const int row0 = blockIdx.x * 128, col0 = blockIdx.y * 256;
    const int r0s = tid >> 2, c0s = tid & 3;

    int offA[4], offB[4];
#pragma unroll
    for (int i = 0; i < 4; ++i) {
        const int r = wm * 64 + i * 16 + fr;
        offA[i] = r * 64 + ((fq ^ ((r >> 1) & 3)) << 4);
    }
#pragma unroll
    for (int j = 0; j < 4; ++j) {
        const int r = wn * 64 + j * 16 + fr;
        offB[j] = r * 64 + ((fq ^ ((r >> 1) & 3)) << 4);
    }

    auto stageAhl = [&](int s) {
        char* base = (char*)lds + (s % 3) * 49152;
        const int r = r0s;
        const int c = c0s ^ ((r >> 1) & 3);
        const size_t g = (size_t)(row0 + r) * D_DIM + s * 32 + c * 8;
        GLOAD16(Ah + g, base + tid * 16);
        GLOAD16(Al + g, base + 8192 + tid * 16);
    };
    auto stageBh = [&](int s) {
        char* base = (char*)lds + (s % 3) * 49152 + 16384;
#pragma unroll
        for (int j = 0; j < 2; ++j) {
            const int r = j * 128 + r0s;
            const int c = c0s ^ ((r >> 1) & 3);
            GLOAD16(Wh + (size_t)(col0 + r) * D_DIM + s * 32 + c * 8,
                    base + j * 8192 + tid * 16);
        }
    };
    auto stageBl = [&](int s) {
        char* base = (char*)lds + (s % 3) * 49152 + 32768;
#pragma unroll
        for (int j = 0; j < 2; ++j) {
            const int r = j * 128 + r0s;
            const int c = c0s ^ ((r >> 1) & 3);
            GLOAD16(Wl + (size_t)(col0 + r) * D_DIM + s * 32 + c * 8,
                    base + j * 8192 + tid * 16);
        }
    };

    f32x4 acc[4][4];
#pragma unroll
    for (int i = 0; i < 4; ++i)
#pragma unroll
        for (int j = 0; j < 4; ++j) acc[i][j] = (f32x4){0.f, 0.f, 0.f, 0.f};

    stageAhl(0); stageBh(0); stageBl(0);
    stageAhl(1); stageBh(1); stageBl(1);
    WAITVM(6); SBAR(); SCHED0();

    for (int t = 0; t < NT; ++t) {
        const char* base = (const char*)lds + (t % 3) * 49152;
        short8 afh[4], afl[4], bfh[4], bfl[4];
#pragma unroll
        for (int i = 0; i < 4; ++i) afh[i] = *(const short8*)(base + offA[i]);
#pragma unroll
        for (int j = 0; j < 4; ++j) bfh[j] = *(const short8*)(base + 16384 + offB[j]);
        if (t + 2 < NT) stageBh(t + 2);
        SBAR();
        PRIO(1);
#pragma unroll
        for (int i = 0; i < 4; ++i)
#pragma unroll
            for (int j = 0; j < 4; ++j)
                acc[i][j] = __builtin_amdgcn_mfma_f32_16x16x32_bf16(afh[i], bfh[j], acc[i][j], 0, 0, 0);
        PRIO(0);
#pragma unroll
        for (int j = 0; j < 4; ++j) bfl[j] = *(const short8*)(base + 32768 + offB[j]);
        if (t + 2 < NT) stageBl(t + 2);
        SBAR();
        PRIO(1);
#pragma unroll
        for (int i = 0; i < 4; ++i)
#pragma unroll
            for (int j = 0; j < 4; ++j)
                acc[i][j] = __builtin_amdgcn_mfma_f32_16x16x32_bf16(afh[i], bfl[j], acc[i][j], 0, 0, 0);
        PRIO(0);
#pragma unroll
        for (int i = 0; i < 4; ++i) afl[i] = *(const short8*)(base + 8192 + offA[i]);
        if (t + 2 < NT) stageAhl(t + 2);
        SBAR();
        PRIO(1);
#pragma unroll
        for (int i = 0; i < 4; ++i)
#pragma unroll
            for (int j = 0; j < 4; ++j)
                acc[i][j] = __builtin_amdgcn_mfma_f32_16x16x32_bf16(afl[i], bfh[j], acc[i][j], 0, 0, 0);
        PRIO(0);
        if (t + 1 < NT) {
            if (t + 2 < NT) { WAITVM(6); }
            else            { WAITVM(0); }
            SBAR(); SCHED0();
        }
    }

    if (EPI == 2) {
        // E-prefetch to registers FIRST (input arrays, independent of LDS) —
        // HBM latency hides under the two barriers + lt writes below.
        const int row = tid >> 2, q = tid & 3;
        const int rg  = row0 + row;
        short8 ehr[8], elr[8];
        if (rg > 0) {
            const u16* ehp = Eh + (size_t)(rg - 1) * D_DIM + col0 + q * 64;
            const u16* elp = El + (size_t)(rg - 1) * D_DIM + col0 + q * 64;
#pragma unroll
            for (int k8 = 0; k8 < 8; ++k8) {
                ehr[k8] = *(const short8*)(ehp + k8 * 8);
                elr[k8] = *(const short8*)(elp + k8 * 8);
            }
        }
        // redistribute t through LDS (staging bufs dead)
        __syncthreads();
        float* lt = (float*)lds;             // [128][260] = 133120 B
#pragma unroll
        for (int i = 0; i < 4; ++i)
#pragma unroll
            for (int j = 0; j < 4; ++j) {
                const int rl = wm * 64 + i * 16 + fq * 4;
                const int cl = wn * 64 + j * 16 + fr;
#pragma unroll
                for (int rr = 0; rr < 4; ++rr)
                    lt[(rl + rr) * 260 + cl] = acc[i][j][rr];
            }
        __syncthreads();
        float s = 0.f;
        if (rg > 0) {
            const float* ltp = lt + row * 260 + q * 64;
#pragma unroll
            for (int k8 = 0; k8 < 8; ++k8) {
#pragma unroll
                for (int e = 0; e < 8; ++e) {
                    const float ev = bf2f((u16)ehr[k8][e]) + bf2f((u16)elr[k8][e]);
                    s = fmaf(ltp[k8 * 8 + e], ev, s);
                }
            }
        }
        Pd[(size_t)(blockIdx.y * 4 + q) * (gridDim.x * 128) + rg] = s;
        return;
    }
#pragma unroll
    for (int i = 0; i < 4; ++i)
#pragma unroll
        for (int j = 0; j < 4; ++j) {
            const int r0 = row0 + wm * 64 + i * 16 + fq * 4;
            const int c  = col0 + wn * 64 + j * 16 + fr;
#pragma unroll
            for (int rr = 0; rr < 4; ++rr) {
                const float v = acc[i][j][rr];
                if (EPI == 0) {
                    const u16 h = f2bf(v);
                    Chi[(size_t)(r0 + rr) * D_DIM + c] = h;
                    Clo[(size_t)(r0 + rr) * D_DIM + c] = f2bf(v - bf2f(h));
                } else {
                    Cf[(size_t)(r0 + rr) * D_DIM + c] = v;
                }
            }
        }
}

// ===========================================================================
// norm2: fused dual-norm GEMM (round-7 form).
// ===========================================================================
__global__ __launch_bounds__(512) void norm2(const u16* __restrict__ A,
                                             const u16* __restrict__ Bq,
                                             const u16* __restrict__ Bk,
                                             float* __restrict__ Pq,
                                             float* __restrict__ Pk) {
    constexpr int NT = 32;
    __shared__ u16 lds[3 * 20480];
    const int tid = threadIdx.x;
    const int lane = tid & 63, wid = tid >> 6;
    const int wm = wid >> 2, wn = wid & 3;
    const int fr = lane & 15, fq = lane >> 4;
    const int row0 = blockIdx.x * 128, col0 = blockIdx.y * 256;
    const int r0s = tid >> 2, c0s = tid & 3;

    int offA[4], offB[4];
#pragma unroll
    for (int i = 0; i < 4; ++i) {
        const int r = wm * 64 + i * 16 + fr;
        offA[i] = r * 64 + ((fq ^ ((r >> 1) & 3)) << 4);
    }
#pragma unroll
    for (int j = 0; j < 4; ++j) {
        const int r = wn * 64 + j * 16 + fr;
        offB[j] = r * 64 + ((fq ^ ((r >> 1) & 3)) << 4);
    }

    auto stageA = [&](int s) {
        char* base = (char*)lds + (s % 3) * 40960;
        const int r = r0s;
        const int c = c0s ^ ((r >> 1) & 3);
        GLOAD16(A + (size_t)(row0 + r) * D_DIM + s * 32 + c * 8, base + tid * 16);
    };
    auto stageBq = [&](int s) {
        char* base = (char*)lds + (s % 3) * 40960 + 8192;
#pragma unroll
        for (int j = 0; j < 2; ++j) {
            const int r = j * 128 + r0s;
            const int c = c0s ^ ((r >> 1) & 3);
            GLOAD16(Bq + (size_t)(col0 + r) * D_DIM + s * 32 + c * 8,
                    base + j * 8192 + tid * 16);
        }
    };
    auto stageBk = [&](int s) {
        char* base = (char*)lds + (s % 3) * 40960 + 24576;
#pragma unroll
        for (int j = 0; j < 2; ++j) {
            const int r = j * 128 + r0s;
            const int c = c0s ^ ((r >> 1) & 3);
            GLOAD16(Bk + (size_t)(col0 + r) * D_DIM + s * 32 + c * 8,
                    base + j * 8192 + tid * 16);
        }
    };

    f32x4 accq[4][4], acck[4][4];
#pragma unroll
    for (int i = 0; i < 4; ++i)
#pragma unroll
        for (int j = 0; j < 4; ++j) {
            accq[i][j] = (f32x4){0.f, 0.f, 0.f, 0.f};
            acck[i][j] = (f32x4){0.f, 0.f, 0.f, 0.f};
        }

    stageA(0); stageBq(0); stageBk(0);
    stageA(1); stageBq(1); stageBk(1);
    WAITVM(5); SBAR(); SCHED0();

    for (int t = 0; t < NT; ++t) {
        const char* base = (const char*)lds + (t % 3) * 40960;
        short8 af[4], bq[4], bk[4];
#pragma unroll
        for (int i = 0; i < 4; ++i) af[i] = *(const short8*)(base + offA[i]);
#pragma unroll
        for (int j = 0; j < 4; ++j) bq[j] = *(const short8*)(base + 8192 + offB[j]);
        if (t + 2 < NT) { stageA(t + 2); stageBq(t + 2); }
        SBAR();
        PRIO(1);
#pragma unroll
        for (int i = 0; i < 4; ++i)
#pragma unroll
            for (int j = 0; j < 4; ++j)
                accq[i][j] = __builtin_amdgcn_mfma_f32_16x16x32_bf16(af[i], bq[j], accq[i][j], 0, 0, 0);
        PRIO(0);
#pragma unroll
        for (int j = 0; j < 4; ++j) bk[j] = *(const short8*)(base + 24576 + offB[j]);
        if (t + 2 < NT) stageBk(t + 2);
        SBAR();
        PRIO(1);
#pragma unroll
        for (int i = 0; i < 4; ++i)
#pragma unroll
            for (int j = 0; j < 4; ++j)
                acck[i][j] = __builtin_amdgcn_mfma_f32_16x16x32_bf16(af[i], bk[j], acck[i][j], 0, 0, 0);
        PRIO(0);
        if (t + 1 < NT) {
            if (t + 2 < NT) { WAITVM(5); }
            else            { WAITVM(0); }
            SBAR(); SCHED0();
        }
    }

    const int Ltot = gridDim.x * 128;
#pragma unroll
    for (int i = 0; i < 4; ++i)
#pragma unroll
        for (int rr = 0; rr < 4; ++rr) {
            const int r = row0 + wm * 64 + i * 16 + fq * 4 + rr;
            float sq = 0.f, sk = 0.f;
#pragma unroll
            for (int j = 0; j < 4; ++j) {
                sq += accq[i][j][rr] * accq[i][j][rr];
                sk += acck[i][j][rr] * acck[i][j][rr];
            }
#pragma unroll
            for (int off = 1; off < 16; off <<= 1) {
                sq += __shfl_xor(sq, off);
                sk += __shfl_xor(sk, off);
            }
            if (fr == 0) {
                Pq[(size_t)(blockIdx.y * 4 + wn) * Ltot + r] = sq;
                Pk[(size_t)(blockIdx.y * 4 + wn) * Ltot + r] = sk;
            }
        }
}

// ---------------------------------------------------------------------------
// gemm_dd2: dual D x D bf16 GEMM (z=0: A@W0^T -> C0, z=1: A@W1^T -> C1).
// ---------------------------------------------------------------------------
__global__ __launch_bounds__(256) void gemm_dd2(const u16* __restrict__ A,
                                                const u16* __restrict__ W0,
                                                const u16* __restrict__ W1,
                                                u16* __restrict__ C0,
                                                u16* __restrict__ C1) {
    __shared__ u16 lA[128 * 32];
    __shared__ u16 lB[128 * 32];
    const u16* W = blockIdx.z ? W1 : W0;
    u16* Cbf     = blockIdx.z ? C1 : C0;
    const int tid  = threadIdx.x;
    const int lane = tid & 63, wid = tid >> 6;
    const int wy = wid & 1, wx = wid >> 1;
    const int fr = lane & 15, fq = lane >> 4;
    const int row0 = blockIdx.x * 128;
    const int col0 = blockIdx.y * 128;

    const int rS   = tid >> 2;
    const int subS = (tid & 3) ^ ((rS >> 1) & 3);
    const u16* gA = A + (size_t)(row0 + rS) * D_DIM + subS * 8;
    const u16* gB = W + (size_t)(col0 + rS) * D_DIM + subS * 8;
    char* lA0 = (char*)lA + tid * 16;
    char* lB0 = (char*)lB + tid * 16;
    const size_t rowStep = (size_t)64 * D_DIM;

    int offA[4], offB[4];
#pragma unroll
    for (int i = 0; i < 4; ++i) {
        const int ra = wy * 64 + i * 16 + fr;
        const int rb = wx * 64 + i * 16 + fr;
        offA[i] = ra * 64 + ((fq ^ ((ra >> 1) & 3)) << 4);
        offB[i] = rb * 64 + ((fq ^ ((rb >> 1) & 3)) << 4);
    }

    f32x4 acc[4][4];
#pragma unroll
    for (int i = 0; i < 4; ++i)
#pragma unroll
        for (int j = 0; j < 4; ++j) acc[i][j] = (f32x4){0.f, 0.f, 0.f, 0.f};

    for (int k0 = 0; k0 < D_DIM; k0 += 32) {
        __syncthreads();
        GLOAD16(gA + k0, lA0);
        GLOAD16(gA + k0 + rowStep, lA0 + 4096);
        GLOAD16(gB + k0, lB0);
        GLOAD16(gB + k0 + rowStep, lB0 + 4096);
        __syncthreads();
        short8 af[4], bf[4];
#pragma unroll
        for (int i = 0; i < 4; ++i) af[i] = *(const short8*)((const char*)lA + offA[i]);
#pragma unroll
        for (int j = 0; j < 4; ++j) bf[j] = *(const short8*)((const char*)lB + offB[j]);
#pragma unroll
        for (int i = 0; i < 4; ++i)
#pragma unroll
            for (int j = 0; j < 4; ++j)
                acc[i][j] = __builtin_amdgcn_mfma_f32_16x16x32_bf16(af[i], bf[j], acc[i][j], 0, 0, 0);
    }
#pragma unroll
    for (int i = 0; i < 4; ++i)
#pragma unroll
        for (int j = 0; j < 4; ++j) {
            const int r0 = row0 + wy * 64 + i * 16 + fq * 4;
            const int c  = col0 + wx * 64 + j * 16 + fr;
#pragma unroll
            for (int r = 0; r < 4; ++r)
                Cbf[(size_t)(r0 + r) * D_DIM + c] = f2bf(acc[i][j][r]);
        }
}

// ===========================================================================
// prep_all: all weight preprocessing in one dispatch. grid (32,32,8), 256 thr.
// ===========================================================================
__global__ __launch_bounds__(256) void prep_all(const float* __restrict__ Wq,
                                                const float* __restrict__ Wk,
                                                const float* __restrict__ Wr,
                                                const float* __restrict__ We,
                                                const float* __restrict__ Wm,
                                                const float* __restrict__ Wd,
                                                u16* __restrict__ WqTh, u16* __restrict__ WqTl,
                                                u16* __restrict__ WkTh, u16* __restrict__ WkTl,
                                                u16* __restrict__ WmTb, u16* __restrict__ WrTb,
                                                u16* __restrict__ Wqb, u16* __restrict__ Wkb,
                                                u16* __restrict__ Wdb,
                                                u16* __restrict__ Weh, u16* __restrict__ Wel) {
    const int task = blockIdx.z;
    if (task < 4) {
        __shared__ float tile[32][33];
        const float* W = (task == 0) ? Wq : (task == 1) ? Wk : (task == 2) ? Wm : Wr;
        u16* Th = (task == 0) ? WqTh : (task == 1) ? WkTh : (task == 2) ? WmTb : WrTb;
        u16* Tl = (task == 0) ? WqTl : (task == 1) ? WkTl : nullptr;
        const int e0 = blockIdx.x * 32, d0 = blockIdx.y * 32;
        const int tx = threadIdx.x & 31, ty = threadIdx.x >> 5;
#pragma unroll
        for (int i = 0; i < 32; i += 8)
            tile[ty + i][tx] = W[(size_t)(e0 + ty + i) * D_DIM + d0 + tx];
        __syncthreads();
#pragma unroll
        for (int i = 0; i < 32; i += 8) {
            float v = tile[tx][ty + i];
            u16 h = f2bf(v);
            Th[(size_t)(d0 + ty + i) * D_DIM + e0 + tx] = h;
            if (Tl) Tl[(size_t)(d0 + ty + i) * D_DIM + e0 + tx] = f2bf(v - bf2f(h));
        }
    } else {
        const int idx = (blockIdx.y * 32 + blockIdx.x) * 256 + threadIdx.x;  // < 262144
        if (task == 7) {
            float4 v = ((const float4*)We)[idx];
            ushort4 h, l;
            h.x = f2bf(v.x); l.x = f2bf(v.x - bf2f(h.x));
            h.y = f2bf(v.y); l.y = f2bf(v.y - bf2f(h.y));
            h.z = f2bf(v.z); l.z = f2bf(v.z - bf2f(h.z));
            h.w = f2bf(v.w); l.w = f2bf(v.w - bf2f(h.w));
            ((ushort4*)Weh)[idx] = h;
            ((ushort4*)Wel)[idx] = l;
        } else {
            const float* S = (task == 4) ? Wq : (task == 5) ? Wk : Wd;
            u16* D = (task == 4) ? Wqb : (task == 5) ? Wkb : Wdb;
            float4 v = ((const float4*)S)[idx];
            ushort4 o = {f2bf(v.x), f2bf(v.y), f2bf(v.z), f2bf(v.w)};
            ((ushort4*)D)[idx] = o;
        }
    }
}

// ---------------------------------------------------------------------------
// small kernels
// ---------------------------------------------------------------------------
__global__ void split_bf16(const float* __restrict__ src, u16* __restrict__ hi,
                           u16* __restrict__ lo, int n4) {
    int i = blockIdx.x * 256 + threadIdx.x;
    if (i >= n4) return;
    float4 v = ((const float4*)src)[i];
    ushort4 h, l;
    h.x = f2bf(v.x); l.x = f2bf(v.x - bf2f(h.x));
    h.y = f2bf(v.y); l.y = f2bf(v.y - bf2f(h.y));
    h.z = f2bf(v.z); l.z = f2bf(v.z - bf2f(h.z));
    h.w = f2bf(v.w); l.w = f2bf(v.w - bf2f(h.w));
    ((ushort4*)hi)[i] = h;
    ((ushort4*)lo)[i] = l;
}

// combine fused-router partials -> p -> gates a, bs
__global__ void combine_router(const float* __restrict__ pd,
                               const float* __restrict__ pq,
                               const float* __restrict__ pk,
                               const int* __restrict__ cu, int nseq,
                               float* __restrict__ a, float* __restrict__ bs,
                               int L) {
    int l = blockIdx.x * 256 + threadIdx.x;
    if (l >= L) return;
    float dot = 0.f, q2 = 0.f, k2 = 0.f;
#pragma unroll
    for (int j = 0; j < 16; ++j) {
        dot += pd[(size_t)j * L + l];
        k2  += pk[(size_t)j * L + l];
        if (l > 0) q2 += pq[(size_t)j * L + l - 1];
    }
    float pv;
    if (l == 0) pv = 1.f;
    else {
        float dn = fmaxf(sqrtf(q2), 1e-12f) * fmaxf(sqrtf(k2), 1e-12f);
        pv = 0.5f * (1.f - dot / dn);
    }
    bool start = false;
    for (int s = 0; s < nseq; ++s) start = start || (cu[s] == l);
    if (start) pv = 1.f;
    bool mask = pv > 0.5f;
    float pc  = fminf(fmaxf(pv, 1e-4f), 1.f - 1e-4f);
    a[l]  = start ? 0.f : (mask ? (1.f - pc) : 1.f);
    bs[l] = mask ? pc : 0.f;
}

// ---------------------------------------------------------------------------
// scan (bf16 z storage, f32 running state)
// ---------------------------------------------------------------------------
__global__ __launch_bounds__(256) void scan_local(const float* __restrict__ a,
                                                  const float* __restrict__ bs,
                                                  u16* __restrict__ m,
                                                  float* __restrict__ P) {
    __shared__ float a_s[CL], b_s[CL];
    const int chunk = blockIdx.x;
    const int d     = blockIdx.y * 256 + threadIdx.x;
    const int l0    = chunk * CL;
    for (int i = threadIdx.x; i < CL; i += 256) { a_s[i] = a[l0 + i]; b_s[i] = bs[l0 + i]; }
    __syncthreads();
    if (blockIdx.y == 0 && threadIdx.x == 0) {
        float pp = 1.f;
        for (int i = 0; i < CL; ++i) { pp *= a_s[i]; P[l0 + i] = pp; }
    }
    float h = 0.f;
    u16* mp = m + (size_t)l0 * D_DIM + d;
    for (int i = 0; i < CL; ++i) {
        float mv = bf2f(mp[(size_t)i * D_DIM]);
        h = fmaf(a_s[i], h, b_s[i] * mv);
        mp[(size_t)i * D_DIM] = f2bf(h);
    }
}

__global__ void scan_carry(const u16* __restrict__ y, const float* __restrict__ P,
                           float* __restrict__ carry, int nchunks) {
    const int d = blockIdx.x * 256 + threadIdx.x;
    float H = 0.f;
    for (int c = 0; c < nchunks; ++c) {
        carry[(size_t)c * D_DIM + d] = H;
        const float Ac = P[c * CL + (CL - 1)];
        const float Bc = bf2f(y[((size_t)c * CL + (CL - 1)) * D_DIM + d]);
        H = fmaf(Ac, H, Bc);
    }
}

// ---------------------------------------------------------------------------
extern "C" void kernel_launch(void* const* d_in, const int* in_sizes, int n_in,
                              void* d_out, int out_size, void* d_ws, size_t ws_size,
                              hipStream_t stream) {
    const float* x  = (const float*)d_in[0];
    const float* Wq = (const float*)d_in[1];
    const float* Wk = (const float*)d_in[2];
    const float* Wr = (const float*)d_in[3];
    const float* We = (const float*)d_in[4];
    const float* Wm = (const float*)d_in[5];
    const float* Wd = (const float*)d_in[6];
    const int*   cu = (const int*)d_in[7];
    const int L    = in_sizes[0] / D_DIM;      // 32768
    const int nseq = in_sizes[7] - 1;          // 4

    const size_t LD2 = (size_t)L * D_DIM * 2;  // 64 MiB bf16 plane
    const int nLD4 = L * D_DIM / 4;
    const int nchunks = L / CL;

    // ws: R1a x_hi -> z | R1b x_lo -> {Wdmb,Wdrb} | R2a enc_hi | R2b enc_lo
    //     | scalars (av, bs, P, carry)
    char* ws = (char*)d_ws;
    u16*   xh   = (u16*)ws;
    u16*   xl   = (u16*)(ws + LD2);
    u16*   zbuf = (u16*)ws;
    u16*   Wdmb = (u16*)(ws + LD2);                 // xl dead after enc
    u16*   Wdrb = (u16*)(ws + LD2 + (2u << 20));
    u16*   ench = (u16*)(ws + 2 * LD2);
    u16*   encl = (u16*)(ws + 3 * LD2);
    float* av   = (float*)(ws + 4 * LD2);
    float* bs   = av + L;
    float* P    = bs + L;
    float* carry= P  + L;                      // [nchunks, D] = 256 KB

    // d_out scratch (ALL dead before the final gemm256<3> writes out):
    char* dob = (char*)d_out;
    u16* Weh   = (u16*)dob;
    u16* Wel   = (u16*)(dob + (2u << 20));
    u16* WqTh  = (u16*)(dob + (4u << 20));
    u16* WqTl  = (u16*)(dob + (6u << 20));
    u16* WkTh  = (u16*)(dob + (8u << 20));
    u16* WkTl  = (u16*)(dob + (10u << 20));
    u16* Mh    = (u16*)(dob + (16u << 20));
    u16* Ml    = (u16*)(dob + (18u << 20));
    u16* Wqb   = (u16*)(dob + (20u << 20));
    u16* Wkb   = (u16*)(dob + (22u << 20));
    u16* Wdb   = (u16*)(dob + (24u << 20));
    u16* WmTb  = (u16*)(dob + (26u << 20));
    u16* WrTb  = (u16*)(dob + (28u << 20));
    float* partdot = (float*)(dob + (34u << 20));   // [16][L] = 2 MB
    float* partnq  = (float*)(dob + (36u << 20));
    float* partnk  = (float*)(dob + (38u << 20));
    float* out = (float*)d_out;

    dim3 gX3L(L / 128, D_DIM / 256);           // (256, 4)
    dim3 gX3D(D_DIM / 128, D_DIM / 256);       // (8, 4)
    dim3 g256(L / 256, D_DIM / 256);           // (128, 4)
    dim3 gDD2(D_DIM / 128, D_DIM / 128, 2);    // (8, 8, 2)
    dim3 gPrep(32, 32, 8);

    // 1. all weight prep in one dispatch; split x
    prep_all<<<gPrep, 256, 0, stream>>>(Wq, Wk, Wr, We, Wm, Wd,
                                        WqTh, WqTl, WkTh, WkTl, WmTb, WrTb,
                                        Wqb, Wkb, Wdb, Weh, Wel);
    split_bf16<<<(nLD4 + 255) / 256, 256, 0, stream>>>(x, xh, xl, nLD4);
    // 2. enc (x3) -> hi/lo planes
    gemm_x3<0><<<gX3L, 512, 0, stream>>>(xh, xl, Weh, Wel, nullptr, ench, encl,
                                         nullptr, nullptr, nullptr);
    // 3. Wdm = Wd@Wm, Wdr = Wd@Wr (dual dispatch; xl region now dead)
    gemm_dd2<<<gDD2, 256, 0, stream>>>(Wdb, WmTb, WrTb, Wdmb, Wdrb);
    // 4. M = Wq^T @ Wk (x3) -> split planes directly (EPI=0)
    gemm_x3<0><<<gX3D, 512, 0, stream>>>(WqTh, WqTl, WkTh, WkTl, nullptr, Mh, Ml,
                                         nullptr, nullptr, nullptr);
    // 5. fused t-GEMM + router dot partials (E-prefetch epilogue)
    gemm_x3<2><<<gX3L, 512, 0, stream>>>(ench, encl, Mh, Ml, nullptr, nullptr, nullptr,
                                         ench, encl, partdot);
    // 6. fused q,k norm partials
    norm2<<<gX3L, 512, 0, stream>>>(ench, Wqb, Wkb, partnq, partnk);
    // 7. combine partials -> p -> gates
    combine_router<<<(L + 255) / 256, 256, 0, stream>>>(partdot, partnq, partnk,
                                                        cu, nseq, av, bs, L);
    // 8. z = enc @ Wdm^T (bf16, over dead x_hi region)
    gemm256<0><<<g256, 512, 0, stream>>>(ench, Wdmb, nullptr, zbuf,
                                         nullptr, nullptr, nullptr);
    // 9. scan over z (decode-commuted)
    dim3 gsl(nchunks, D_DIM / 256);
    scan_local<<<gsl, 256, 0, stream>>>(av, bs, zbuf, P);
    scan_carry<<<D_DIM / 256, 256, 0, stream>>>(zbuf, P, carry, nchunks);
    // 10. out = enc @ Wdr^T + z_scanned + P*carry  (fused epilogue, f32 out)
    gemm256<3><<<g256, 512, 0, stream>>>(ench, Wdrb, out, nullptr,
                                         zbuf, P, carry);
}